// Round 11
// baseline (302.795 us; speedup 1.0000x reference)
//
#include <hip/hip_runtime.h>
#include <hip/hip_bf16.h>
#include <stdint.h>

#define DEVI __device__ __forceinline__

namespace {

constexpr int B = 8, T = 2048, C = 3, E = 256, KW = 15, BN = 32;
constexpr float EPS = 1e-5f;

constexpr int XPAD = 8;              // conv_in reach: +/-7
constexpr int XS   = T + 2*XPAD;     // 2064
constexpr int HPAD = 224;            // max reach: 7*32
constexpr int HS   = T + 2*HPAD;     // 2496

// workspace layout (float units)
constexpr size_t O_MEAN = 0;
constexpr size_t O_STD  = 32;
constexpr size_t O_QN   = 64;
constexpr size_t XBUF   = (size_t)B*C*XS;        // 49536
constexpr size_t O_KN   = O_QN + XBUF;
constexpr size_t HBUF   = (size_t)3*B*BN*HS;     // 1,916,928 per buffer
constexpr size_t O_HA   = O_KN + XBUF;
constexpr size_t O_HB   = O_HA + HBUF;
constexpr size_t O_Q    = O_HB + HBUF;           // 3,932,992
constexpr size_t QBUF_H = (size_t)B*T*E/2;       // bf16 buffer in float units (2,097,152)
constexpr size_t O_K    = O_Q + QBUF_H;
constexpr size_t O_V    = O_K + QBUF_H;          // V stored TRANSPOSED: [E][B*T] bf16
constexpr size_t O_PO_HI= O_V + QBUF_H;          // splits 0..2 (3 x QBUF_H) -> end 66.06 MB (proven OK)
// packed weights overlay the PO_hi region (dead until attn writes it):
// wA: conv_mid A-fragment prepack, split-bf16: 3*5*30*2*512 ushort = 460,800 ush = 230,400 fl
constexpr size_t O_WPM  = O_PO_HI;
constexpr size_t O_WPO  = O_WPM + (size_t)245760;        // keep old slot size; wA fits (230,400 < 245,760)
// split 3 + m/l overlay the (already-consumed) qn/kn/h region:
constexpr size_t O_PO_LO= O_QN;                  // 1 split
constexpr size_t O_MLM  = O_PO_LO + QBUF_H;      // 4*B*T floats
constexpr size_t O_MLL  = O_MLM + (size_t)4*B*T; // 4*B*T floats (region consumed before attn)

typedef __attribute__((ext_vector_type(8))) short bfrag;
typedef __attribute__((ext_vector_type(4))) float f32x4;
typedef __attribute__((ext_vector_type(16))) float f32x16;
typedef __attribute__((ext_vector_type(4))) unsigned int u32x4;
typedef __attribute__((ext_vector_type(2))) unsigned int u32x2;

DEVI short f2bf(float f){            // fp32 -> bf16 bits, round-to-nearest-even
  uint32_t u = __builtin_bit_cast(uint32_t, f);
  u = u + 0x7fffu + ((u >> 16) & 1u);
  return (short)(u >> 16);
}
DEVI float bf2f(unsigned short u){
  uint32_t x = (uint32_t)u << 16;
  return __builtin_bit_cast(float, x);
}
DEVI uint32_t cvtpk(float a, float b){   // {bf16(b)<<16 | bf16(a)}, HW RNE
  uint32_t d;
  asm("v_cvt_pk_bf16_f32 %0, %1, %2" : "=v"(d) : "v"(a), "v"(b));
  return d;
}
DEVI f32x16 vzero16(){
  f32x16 v;
  #pragma unroll
  for (int i = 0; i < 16; i++) v[i] = 0.f;
  return v;
}

// 16B global -> LDS DMA. LDS dest must be WAVE-UNIFORM base; HW adds lane*16.
DEVI void gload16(const unsigned short* g, short* l){
  __builtin_amdgcn_global_load_lds((const __attribute__((address_space(1))) void*)g,
                                   (__attribute__((address_space(3))) void*)l, 16, 0, 0);
}

// fused prep: [0,1536) h halos, 1536 qn/kn pads, [1537,2437) conv_mid wA prepack
// (split-bf16 A-fragments), [2437,2533) conv_out weight pack, [2533,2557) RevIN.
__global__ __launch_bounds__(256) void k_prep(
    float* __restrict__ ws,
    const float* __restrict__ query_in, const float* __restrict__ key_in,
    const float* __restrict__ revin_w, const float* __restrict__ revin_b,
    const float* __restrict__ qm, const float* __restrict__ km, const float* __restrict__ vm,
    const float* __restrict__ qo, const float* __restrict__ ko, const float* __restrict__ vo){
  __shared__ float r1[256], r2[256];
  __shared__ float sm, sinv;
  const int r = blockIdx.x;
  if (r < 1536){
    float* row = ws + (r < 768 ? O_HA : O_HB) + (size_t)(r & 767)*HS;
    const int t = threadIdx.x;
    if (t < HPAD) row[t] = 0.f;                 // head [0, 224)
    else if (t < 2*HPAD) row[T + t] = 0.f;      // tail [HPAD+T, HS)
  } else if (r == 1536){
    for (int z = threadIdx.x; z < 768; z += 256){
      int buf = z >= 384; int zz = z & 383;
      int rw = zz >> 4; int p = zz & 15;
      float* base = ws + (buf ? O_KN : O_QN) + (size_t)rw*XS;
      base[p < 8 ? p : (XPAD + T + p - 8)] = 0.f;
    }
  } else if (r < 2437){
    // conv_mid A-frag prepack: wA[(netlyr*30+kb)*1024 + half*512 + lane*8 + j] (ushort)
    // kb=(kk<<1)|i16; lane l: o=l&31, hi=l>>5; element j -> W[o][i=i16*16+hi*8+j][kk].
    // half 0 = bf16(w), half 1 = bf16(w - hi_part)  (split-bf16, ~2^-17 rel error)
    unsigned short* wA = (unsigned short*)(ws + O_WPM);
    int p = (r - 1537)*256 + threadIdx.x;       // [0, 230400)
    int j  = p & 7;
    int l  = (p >> 3) & 63;
    int kb = (p >> 9) % 30;
    int netlyr = p / 15360;                      // [0,15)
    int net = netlyr / 5, lyr = netlyr % 5;
    int o  = l & 31, hi = l >> 5;
    int i  = (kb & 1)*16 + hi*8 + j;
    int kk = kb >> 1;
    const float* src = (net==0 ? qm : (net==1 ? km : vm));
    float w = src[(((size_t)lyr*32 + o)*32 + i)*15 + kk];
    unsigned short wh = (unsigned short)f2bf(w);
    unsigned short wl = (unsigned short)f2bf(w - bf2f(wh));
    size_t base = ((size_t)(netlyr*30 + kb))*1024 + l*8 + j;
    wA[base]       = wh;
    wA[base + 512] = wl;
  } else if (r < 2533){
    // conv_out weight pack: [net][i][e]
    float* wpo = ws + O_WPO;
    int idx = (r - 2437)*256 + threadIdx.x;     // [0, 24576)
    int e = idx & 255;
    int i = (idx >> 8) & 31;
    int net = idx >> 13;
    const float* src = (net==0 ? qo : (net==1 ? ko : vo));
    wpo[idx] = src[(size_t)e*32 + i];
  } else {
    // RevIN stats + norm for one (b,c)
    const int bc = r - 2533;
    const int b = bc / C, c = bc % C;
    float* meanp = ws + O_MEAN; float* stdp = ws + O_STD;
    float* qn = ws + O_QN;      float* kn = ws + O_KN;
    float s = 0.f, s2 = 0.f;
    for (int t = threadIdx.x; t < T; t += 256){
      float v = key_in[((size_t)(b*T) + t)*C + c];
      s += v; s2 += v*v;
    }
    r1[threadIdx.x] = s; r2[threadIdx.x] = s2;
    __syncthreads();
    for (int st = 128; st > 0; st >>= 1){
      if (threadIdx.x < st){ r1[threadIdx.x] += r1[threadIdx.x+st]; r2[threadIdx.x] += r2[threadIdx.x+st]; }
      __syncthreads();
    }
    if (threadIdx.x == 0){
      float m = r1[0] / (float)T;
      float var = r2[0] / (float)T - m*m;
      float sd = sqrtf(var + EPS);
      meanp[bc] = m; stdp[bc] = sd; sm = m; sinv = 1.f/sd;
    }
    __syncthreads();
    const float m = sm, inv = sinv, wvv = revin_w[c], bvv = revin_b[c];
    for (int t = threadIdx.x; t < T; t += 256){
      size_t src = ((size_t)(b*T) + t)*C + c;
      size_t dst = ((size_t)(b*C) + c)*XS + XPAD + t;
      qn[dst] = (query_in[src] - m) * inv * wvv + bvv;
      kn[dst] = (key_in[src]   - m) * inv * wvv + bvv;
    }
  }
}

// conv in: C=3 -> BN=32, k=15, dil=1, ReLU. grid = 3*B*BN, block = one (net,b,o) row.
__global__ __launch_bounds__(256) void k_conv_in(
    const float* __restrict__ qn, const float* __restrict__ kn,
    const float* __restrict__ wq, const float* __restrict__ bq,
    const float* __restrict__ wk, const float* __restrict__ bk,
    const float* __restrict__ wv, const float* __restrict__ bv,
    float* __restrict__ hout){
  __shared__ float xs[C*XS];
  const int net = blockIdx.x / (B*BN);
  const int rem = blockIdx.x % (B*BN);
  const int b = rem / BN, o = rem % BN;
  const float* x    = (net==0 ? qn : kn) + (size_t)b*C*XS;
  const float* w    = (net==0 ? wq : (net==1 ? wk : wv)) + o*C*KW;
  const float* bias = (net==0 ? bq : (net==1 ? bk : bv));
  for (int i = threadIdx.x; i < C*XS; i += 256) xs[i] = x[i];
  __syncthreads();
  const float bo = bias[o];
  float* orow = hout + (((size_t)(net*B + b))*BN + o)*HS + HPAD;
  for (int j = 0; j < 8; j++){
    int t = j*256 + threadIdx.x;
    float acc = bo;
    #pragma unroll
    for (int c = 0; c < C; c++)
      #pragma unroll
      for (int kk = 0; kk < KW; kk++)
        acc += xs[c*XS + XPAD + t + kk - 7] * w[c*KW + kk];
    orow[t] = fmaxf(acc, 0.f);
  }
}

// dilated conv BN->BN as split-bf16 MFMA GEMM. grid = 3*8*16 = 384, 256 thr (4 waves).
// (structure proven r8; unroll-6 kept from r10, neutral)
template<int DIL>
__global__ __launch_bounds__(256) void k_conv_mid(
    const float* __restrict__ hin, float* __restrict__ hout,
    const unsigned short* __restrict__ wA,
    const float* __restrict__ bq, const float* __restrict__ bk, const float* __restrict__ bv,
    int layer){
  constexpr int WT  = 128 + 14*DIL;              // staged t-window rows
  constexpr int NRR = (WT + 15)/16;
  __shared__ __align__(16) unsigned short Xh[WT*40];
  __shared__ __align__(16) unsigned short Xl[WT*40];

  const int net = blockIdx.x >> 7;               // 128 blocks per net
  const int rem = blockIdx.x & 127;
  const int b  = rem >> 4;
  const int tt = rem & 15;
  const int netb = net*B + b;
  const int tid  = threadIdx.x;
  const int wv   = __builtin_amdgcn_readfirstlane(tid >> 6);
  const int lane = tid & 63;
  const int l5   = lane & 31;
  const int hi   = lane >> 5;

  // ---- stage X^T (bf16 split) ----
  {
    const int ip = tid >> 4;                     // i-pair 0..15 (i = 2*ip, 2*ip+1)
    const int tl = tid & 15;                     // lanes 0-15 consecutive t -> coalesced
    const int gt0 = HPAD + tt*128 - 7*DIL;       // >= 0 (HPAD = 224 = 7*32)
    const float* r0 = hin + ((size_t)(netb*32 + 2*ip))*HS + gt0;
    const float* r1 = r0 + HS;
    unsigned int* xhw = (unsigned int*)Xh;
    unsigned int* xlw = (unsigned int*)Xl;
    #pragma unroll
    for (int rr = 0; rr < NRR; rr++){
      int t = rr*16 + tl;
      if (t < WT){
        float a = r0[t], bb = r1[t];
        uint32_t hp = cvtpk(a, bb);
        float la = a  - bf2f((unsigned short)(hp & 0xffffu));
        float lb = bb - bf2f((unsigned short)(hp >> 16));
        uint32_t lp = cvtpk(la, lb);
        xhw[t*20 + ip] = hp;
        xlw[t*20 + ip] = lp;
      }
    }
  }
  __syncthreads();

  // ---- MFMA K-loop ----
  const unsigned short* wAl = wA + (size_t)(net*5 + layer)*30*1024;
  f32x16 a0 = vzero16(), a1 = vzero16(), a2 = vzero16();
  #pragma unroll 6
  for (int kb = 0; kb < 30; kb++){
    const int kk  = kb >> 1;
    const int i16 = kb & 1;
    bfrag Ah = *(const bfrag*)(wAl + (size_t)kb*1024 + lane*8);
    bfrag Al = *(const bfrag*)(wAl + (size_t)kb*1024 + 512 + lane*8);
    const int row = wv*32 + l5 + kk*DIL;         // <= 127 + 14*DIL = WT-1
    bfrag Bh = *(const bfrag*)&Xh[row*40 + (i16*2 + hi)*8];
    bfrag Bl = *(const bfrag*)&Xl[row*40 + (i16*2 + hi)*8];
    a0 = __builtin_amdgcn_mfma_f32_32x32x16_bf16(Ah, Bh, a0, 0, 0, 0);
    a1 = __builtin_amdgcn_mfma_f32_32x32x16_bf16(Ah, Bl, a1, 0, 0, 0);
    a2 = __builtin_amdgcn_mfma_f32_32x32x16_bf16(Al, Bh, a2, 0, 0, 0);
  }

  // ---- epilogue: bias + ReLU, store [o][t] (per r: 2x128B coalesced) ----
  const float* bias = (net==0 ? bq : (net==1 ? bk : bv)) + layer*BN;
  const int tg = tt*128 + wv*32 + l5;
  float* obase = hout + ((size_t)netb*32)*HS + HPAD + tg;
  #pragma unroll
  for (int g = 0; g < 4; g++){
    float4 bg = *(const float4*)(bias + g*8 + 4*hi);
    #pragma unroll
    for (int q = 0; q < 4; q++){
      int o = g*8 + 4*hi + q;
      float v = a0[g*4+q] + a1[g*4+q] + a2[g*4+q] + ((const float*)&bg)[q];
      obase[(size_t)o*HS] = fmaxf(v, 0.f);
    }
  }
}

// 1x1 conv BN -> E, bf16 out, packed weights; q pre-scaled by E^-0.5. grid = 1536.
// V (net==2) is written TRANSPOSED [E][B*T] so attention can stage it coalesced.
__global__ __launch_bounds__(256) void k_conv_out(
    const float* __restrict__ hin, const float* __restrict__ wpo,
    const float* __restrict__ bq, const float* __restrict__ bk, const float* __restrict__ bv,
    unsigned short* __restrict__ qo, unsigned short* __restrict__ ko, unsigned short* __restrict__ vo){
  const int net = blockIdx.x >> 9;
  const int rem = blockIdx.x & 511;
  const int b = rem >> 6;
  const int tt = (rem & 63) >> 2;
  const int eq = rem & 3;
  const int wave = __builtin_amdgcn_readfirstlane(threadIdx.x >> 6);
  const int lane = threadIdx.x & 63;
  const int t0 = tt*128 + lane*2;
  const int e_base = eq*64 + wave*16;
  const float* wb   = wpo + (size_t)net*32*256 + e_base;   // + i*256 per i
  const float* bias = (net==0 ? bq : (net==1 ? bk : bv)) + e_base;
  float acc[16][2];
  #pragma unroll
  for (int j = 0; j < 16; j++){ acc[j][0] = 0.f; acc[j][1] = 0.f; }
  const float* hb = hin + (((size_t)(net*B + b))*BN)*HS + HPAD + t0;
  for (int i = 0; i < BN; i++){
    const float2 xv = *(const float2*)(hb + (size_t)i*HS);
    const float* wi = wb + i*256;
    #pragma unroll
    for (int j = 0; j < 16; j++){
      const float wj = wi[j];
      acc[j][0] += wj*xv.x; acc[j][1] += wj*xv.y;
    }
  }
  if (net != 2){
    const float scale = (net==0) ? 0.0625f : 1.0f;
    unsigned short* outp = (net==0 ? qo : ko);
    #pragma unroll
    for (int z = 0; z < 2; z++){
      bfrag pk[2];
      #pragma unroll
      for (int j = 0; j < 16; j++)
        pk[j>>3][j&7] = f2bf((acc[j][z] + bias[j]) * scale);
      size_t dst = ((size_t)(b*T) + t0 + z)*E + e_base;
      *(bfrag*)&outp[dst]     = pk[0];
      *(bfrag*)&outp[dst + 8] = pk[1];
    }
  } else {
    // transposed V: vo[e][b*T + t]; pack the two adjacent-t bf16 into one dword store.
    unsigned int* vt = (unsigned int*)vo;
    #pragma unroll
    for (int j = 0; j < 16; j++){
      unsigned int lo = (unsigned short)f2bf(acc[j][0] + bias[j]);
      unsigned int hi = (unsigned short)f2bf(acc[j][1] + bias[j]);
      size_t idx = (size_t)(e_base + j)*((size_t)B*T) + (size_t)b*T + t0;
      vt[idx >> 1] = lo | (hi << 16);
    }
  }
}

// flash attention v2: 32x32 MFMA, swapped operands, in-register softmax.
// BQ=128 (4 waves x 32 q-rows, 256 thr), BK=32, split-K=4. grid = B*16*4 = 512.
// r11: QK accumulator split into TWO chains (s0: st 0-7, s1: st 8-15, interleaved)
// to halve the dependent-MFMA latency chain (MfmaUtil 22% @ 2 waves/SIMD was
// chain-latency-consistent); row-max via max3-friendly tree (depth ~3 vs 15).
__global__ __launch_bounds__(256, 2) void k_attn(
    const unsigned short* __restrict__ qbuf, const unsigned short* __restrict__ kbuf,
    const unsigned short* __restrict__ vbufT,
    unsigned short* __restrict__ PO_hi, unsigned short* __restrict__ PO_lo,
    float* __restrict__ MLm, float* __restrict__ MLl){
  __shared__ __align__(16) short Ks[2][32*256];   // K tile, key-major, 512B/row, granule^key&7
  __shared__ __align__(16) short Vs[2][256*32];   // V^T tile, e-major, 64B/row, granule^(e>>1)&3

  const int nid  = ((blockIdx.x & 7) << 6) | (blockIdx.x >> 3);
  const int s    = nid & 3;
  const int qt   = (nid >> 2) & 15;
  const int b    = nid >> 6;
  const int tid  = threadIdx.x;
  const int wv   = __builtin_amdgcn_readfirstlane(tid >> 6);
  const int lane = tid & 63;
  const int l5   = lane & 31;
  const int hi   = lane >> 5;
  const int qrow_base = qt*128 + wv*32;

  bfrag b_q[16];
  {
    const unsigned short* qp = qbuf + ((size_t)(b*T) + qrow_base + l5)*E + hi*8;
    #pragma unroll
    for (int st = 0; st < 16; st++)
      b_q[st] = *(const bfrag*)&qp[st*16];
  }

  f32x16 acc[8];
  #pragma unroll
  for (int nt = 0; nt < 8; nt++) acc[nt] = vzero16();
  float m_run = -1e30f, l_run = 0.f;

  const unsigned short* gks[4]; const unsigned short* gvs[4];
  #pragma unroll
  for (int u = 0; u < 4; u++){
    int lin = u*256 + tid;
    int kr = lin >> 5, kg = lin & 31;
    gks[u] = kbuf + ((size_t)(b*T) + kr)*E + ((kg ^ (kr & 7)) << 3);
    int ve = lin >> 2, vg = lin & 3;
    gvs[u] = vbufT + (size_t)ve*((size_t)B*T) + (size_t)b*T + ((vg ^ ((ve >> 1) & 3)) << 3);
  }
  auto stage = [&](int buf, int j0){
    #pragma unroll
    for (int u = 0; u < 4; u++)
      gload16(gks[u] + (size_t)j0*E, &Ks[buf][u*2048 + wv*512]);
    #pragma unroll
    for (int u = 0; u < 4; u++)
      gload16(gvs[u] + j0, &Vs[buf][u*2048 + wv*512]);
  };

  const int x7 = l5 & 7;
  const int vx = (l5 >> 1) & 3;

  const int kend = s*16 + 16;
  stage(0, s*16*32);
  __syncthreads();
  int cur = 0;

  for (int kbk = s*16; kbk < kend; kbk++){
    if (kbk + 1 < kend) stage(cur ^ 1, (kbk+1)*32);

    // S^T: two interleaved 8-deep chains (halved dependency latency)
    f32x16 s0 = vzero16(), s1 = vzero16();
    __builtin_amdgcn_s_setprio(1);
    #pragma unroll
    for (int st = 0; st < 8; st++){
      bfrag ka = *(const bfrag*)&Ks[cur][l5*256 + (((( st      << 1) | hi) ^ x7) << 3)];
      bfrag kb = *(const bfrag*)&Ks[cur][l5*256 + (((((st + 8) << 1) | hi) ^ x7) << 3)];
      s0 = __builtin_amdgcn_mfma_f32_32x32x16_bf16(ka, b_q[st],     s0, 0, 0, 0);
      s1 = __builtin_amdgcn_mfma_f32_32x32x16_bf16(kb, b_q[st + 8], s1, 0, 0, 0);
    }
    __builtin_amdgcn_s_setprio(0);
    f32x16 sac = s0 + s1;

    // row-max: balanced tree (fuses to v_max3), then pair-lane exchange
    float m0 = fmaxf(fmaxf(sac[0],  sac[1]),  sac[2]);
    float m1 = fmaxf(fmaxf(sac[3],  sac[4]),  sac[5]);
    float m2 = fmaxf(fmaxf(sac[6],  sac[7]),  sac[8]);
    float m3 = fmaxf(fmaxf(sac[9],  sac[10]), sac[11]);
    float m4 = fmaxf(fmaxf(sac[12], sac[13]), sac[14]);
    float mloc = fmaxf(fmaxf(fmaxf(m0, m1), fmaxf(m2, m3)), fmaxf(m4, sac[15]));
    mloc = fmaxf(mloc, __shfl_xor(mloc, 32));

    if (__ballot(mloc > m_run + 8.f)){
      float mn = fmaxf(m_run, mloc);
      float alpha = __expf(m_run - mn);
      m_run = mn;
      l_run *= alpha;
      #pragma unroll
      for (int nt = 0; nt < 8; nt++)
        #pragma unroll
        for (int r = 0; r < 16; r++) acc[nt][r] *= alpha;
    }
    float p[16]; float ls = 0.f;
    #pragma unroll
    for (int r = 0; r < 16; r++){
      p[r] = __expf(sac[r] - m_run);
      ls += p[r];
    }
    l_run += ls;

    uint32_t pk[8], xk[8];
    #pragma unroll
    for (int r = 0; r < 8; r++)
      pk[r] = cvtpk(p[2*r], p[2*r+1]);
    #pragma unroll
    for (int r = 0; r < 8; r++) xk[r] = __shfl_xor(pk[r], 32);
    u32x4 w0, w1;
    w0[0] = hi ? xk[2] : pk[0];  w0[1] = hi ? xk[3] : pk[1];
    w0[2] = hi ? pk[2] : xk[0];  w0[3] = hi ? pk[3] : xk[1];
    w1[0] = hi ? xk[6] : pk[4];  w1[1] = hi ? xk[7] : pk[5];
    w1[2] = hi ? pk[6] : xk[4];  w1[3] = hi ? pk[7] : xk[5];
    bfrag pf0 = __builtin_bit_cast(bfrag, w0);
    bfrag pf1 = __builtin_bit_cast(bfrag, w1);

    __builtin_amdgcn_s_setprio(1);
    #pragma unroll
    for (int nt = 0; nt < 8; nt++){
      bfrag v0 = *(const bfrag*)&Vs[cur][(nt*32 + l5)*32 + (((0 | hi) ^ vx) << 3)];
      acc[nt] = __builtin_amdgcn_mfma_f32_32x32x16_bf16(v0, pf0, acc[nt], 0, 0, 0);
      bfrag v1 = *(const bfrag*)&Vs[cur][(nt*32 + l5)*32 + (((2 | hi) ^ vx) << 3)];
      acc[nt] = __builtin_amdgcn_mfma_f32_32x32x16_bf16(v1, pf1, acc[nt], 0, 0, 0);
    }
    __builtin_amdgcn_s_setprio(0);

    __syncthreads();
    cur ^= 1;
  }

  l_run += __shfl_xor(l_run, 32);
  const float inv_l = 1.f / l_run;
  const int row = qrow_base + l5;
  unsigned short* PO = (s < 3) ? (PO_hi + (size_t)s*((size_t)B*T*E)) : PO_lo;
  const size_t off = ((size_t)(b*T) + row)*E;
  #pragma unroll
  for (int nt = 0; nt < 8; nt++){
    #pragma unroll
    for (int g = 0; g < 4; g++){
      const int e0 = nt*32 + 8*g + 4*hi;
      u32x2 wpair;
      wpair[0] = cvtpk(acc[nt][g*4+0]*inv_l, acc[nt][g*4+1]*inv_l);
      wpair[1] = cvtpk(acc[nt][g*4+2]*inv_l, acc[nt][g*4+3]*inv_l);
      *(u32x2*)&PO[off + e0] = wpair;
    }
  }
  if (hi == 0){
    const size_t rm = ((size_t)(s*B + b))*T + row;
    MLm[rm] = m_run;
    MLl[rm] = l_run;
  }
}

// combine 4 splits + out-projection + RevIN denorm. grid = B*T/32 = 512, 256 thr.
__global__ __launch_bounds__(256) void k_comb(
    const unsigned short* __restrict__ PO_hi, const unsigned short* __restrict__ PO_lo,
    const float* __restrict__ MLm, const float* __restrict__ MLl,
    const float* __restrict__ out_w, const float* __restrict__ out_b,
    const float* __restrict__ revin_w, const float* __restrict__ revin_b,
    const float* __restrict__ meanp, const float* __restrict__ stdp,
    float* __restrict__ out){
  __shared__ float wsh[3*E];
  for (int i = threadIdx.x; i < 3*E; i += 256) wsh[i] = out_w[i];
  __syncthreads();
  const int b  = blockIdx.x >> 6;
  const int rt = blockIdx.x & 63;
  const int row = rt*32 + (threadIdx.x >> 3);
  const int c8 = threadIdx.x & 7;
  const int e0 = c8*32;
  float ms[4], ls[4], wn[4];
  #pragma unroll
  for (int s2 = 0; s2 < 4; s2++){
    const size_t rm = ((size_t)(s2*B + b))*T + row;
    ms[s2] = MLm[rm]; ls[s2] = MLl[rm];
  }
  float mx = fmaxf(fmaxf(ms[0], ms[1]), fmaxf(ms[2], ms[3]));
  float wsum = 0.f;
  #pragma unroll
  for (int s2 = 0; s2 < 4; s2++){ wn[s2] = __expf(ms[s2]-mx)*ls[s2]; wsum += wn[s2]; }
  float inv = 1.f/wsum;
  #pragma unroll
  for (int s2 = 0; s2 < 4; s2++) wn[s2] *= inv;
  const unsigned short* ps[4];
  #pragma unroll
  for (int s2 = 0; s2 < 4; s2++){
    const unsigned short* base = (s2 < 3) ? (PO_hi + (size_t)s2*((size_t)B*T*E)) : PO_lo;
    ps[s2] = base + ((size_t)(b*T) + row)*E + e0;
  }
  float pr[3] = {0.f, 0.f, 0.f};
  #pragma unroll
  for (int u = 0; u < 4; u++){
    float v[8] = {0,0,0,0,0,0,0,0};
    #pragma unroll
    for (int s2 = 0; s2 < 4; s2++){
      bfrag a = *(const bfrag*)&ps[s2][u*8];
      #pragma unroll
      for (int z = 0; z < 8; z++) v[z] += wn[s2]*bf2f((unsigned short)a[z]);
    }
    #pragma unroll
    for (int z = 0; z < 8; z++){
      int e = e0 + u*8 + z;
      pr[0] += v[z]*wsh[e];
      pr[1] += v[z]*wsh[E + e];
      pr[2] += v[z]*wsh[2*E + e];
    }
  }
  #pragma unroll
  for (int c = 0; c < 3; c++){
    pr[c] += __shfl_xor(pr[c], 1);
    pr[c] += __shfl_xor(pr[c], 2);
    pr[c] += __shfl_xor(pr[c], 4);
  }
  if (c8 == 0){
    #pragma unroll
    for (int c = 0; c < 3; c++){
      float val = pr[c] + out_b[c];
      val = (val - revin_b[c]) / revin_w[c];
      val = val * stdp[b*C + c] + meanp[b*C + c];
      out[((size_t)(b*T) + row)*C + c] = val;
    }
  }
}

} // namespace

extern "C" void kernel_launch(void* const* d_in, const int* in_sizes, int n_in,
                              void* d_out, int out_size, void* d_ws, size_t ws_size,
                              hipStream_t stream){
  const float* query_in = (const float*)d_in[0];
  const float* key_in   = (const float*)d_in[1];
  const float* q_w_in   = (const float*)d_in[2];
  const float* q_b_in   = (const float*)d_in[3];
  const float* q_w_mid  = (const float*)d_in[4];
  const float* q_b_mid  = (const float*)d_in[5];
  const float* q_w_out  = (const float*)d_in[6];
  const float* q_b_out  = (const float*)d_in[7];
  const float* k_w_in   = (const float*)d_in[8];
  const float* k_b_in   = (const float*)d_in[9];
  const float* k_w_mid  = (const float*)d_in[10];
  const float* k_b_mid  = (const float*)d_in[11];
  const float* k_w_out  = (const float*)d_in[12];
  const float* k_b_out  = (const float*)d_in[13];
  const float* v_w_in   = (const float*)d_in[14];
  const float* v_b_in   = (const float*)d_in[15];
  const float* v_w_mid  = (const float*)d_in[16];
  const float* v_b_mid  = (const float*)d_in[17];
  const float* v_w_out  = (const float*)d_in[18];
  const float* v_b_out  = (const float*)d_in[19];
  const float* out_w    = (const float*)d_in[20];
  const float* out_b    = (const float*)d_in[21];
  const float* revin_w  = (const float*)d_in[22];
  const float* revin_b  = (const float*)d_in[23];
  float* ws  = (float*)d_ws;
  float* out = (float*)d_out;

  unsigned short* qb = (unsigned short*)(ws + O_Q);
  unsigned short* kb = (unsigned short*)(ws + O_K);
  unsigned short* vb = (unsigned short*)(ws + O_V);
  unsigned short* PO_hi = (unsigned short*)(ws + O_PO_HI);
  unsigned short* PO_lo = (unsigned short*)(ws + O_PO_LO);
  float* MLm = ws + O_MLM;
  float* MLl = ws + O_MLL;
  unsigned short* wA = (unsigned short*)(ws + O_WPM);
  float* wpo = ws + O_WPO;

  hipLaunchKernelGGL(k_prep, dim3(2557), dim3(256), 0, stream,
                     ws, query_in, key_in, revin_w, revin_b,
                     q_w_mid, k_w_mid, v_w_mid, q_w_out, k_w_out, v_w_out);
  hipLaunchKernelGGL(k_conv_in, dim3(3*B*BN), dim3(256), 0, stream,
                     ws+O_QN, ws+O_KN, q_w_in, q_b_in, k_w_in, k_b_in, v_w_in, v_b_in, ws+O_HA);
  float* ha = ws + O_HA;
  float* hb = ws + O_HB;
  hipLaunchKernelGGL(k_conv_mid<2>,  dim3(384), dim3(256), 0, stream, ha, hb,
                     wA, q_b_mid, k_b_mid, v_b_mid, 0);
  hipLaunchKernelGGL(k_conv_mid<4>,  dim3(384), dim3(256), 0, stream, hb, ha,
                     wA, q_b_mid, k_b_mid, v_b_mid, 1);
  hipLaunchKernelGGL(k_conv_mid<8>,  dim3(384), dim3(256), 0, stream, ha, hb,
                     wA, q_b_mid, k_b_mid, v_b_mid, 2);
  hipLaunchKernelGGL(k_conv_mid<16>, dim3(384), dim3(256), 0, stream, hb, ha,
                     wA, q_b_mid, k_b_mid, v_b_mid, 3);
  hipLaunchKernelGGL(k_conv_mid<32>, dim3(384), dim3(256), 0, stream, ha, hb,
                     wA, q_b_mid, k_b_mid, v_b_mid, 4);
  hipLaunchKernelGGL(k_conv_out, dim3(1536), dim3(256), 0, stream,
                     hb, wpo, q_b_out, k_b_out, v_b_out, qb, kb, vb);
  hipLaunchKernelGGL(k_attn, dim3(B*16*4), dim3(256), 0, stream, qb, kb, vb, PO_hi, PO_lo, MLm, MLl);
  hipLaunchKernelGGL(k_comb, dim3(B*T/32), dim3(256), 0, stream,
                     PO_hi, PO_lo, MLm, MLl, out_w, out_b, revin_w, revin_b, ws+O_MEAN, ws+O_STD, out);
}

// Round 12
// 282.707 us; speedup vs baseline: 1.0711x; 1.0711x over previous
//
#include <hip/hip_runtime.h>
#include <hip/hip_bf16.h>
#include <stdint.h>

#define DEVI __device__ __forceinline__

namespace {

constexpr int B = 8, T = 2048, C = 3, E = 256, KW = 15, BN = 32;
constexpr float EPS = 1e-5f;

constexpr int XPAD = 8;              // conv_in reach: +/-7
constexpr int XS   = T + 2*XPAD;     // 2064
constexpr int HPAD = 224;            // max reach: 7*32
constexpr int HS   = T + 2*HPAD;     // 2496

// workspace layout (float units)
constexpr size_t O_MEAN = 0;
constexpr size_t O_STD  = 32;
constexpr size_t O_QN   = 64;
constexpr size_t XBUF   = (size_t)B*C*XS;        // 49536
constexpr size_t O_KN   = O_QN + XBUF;
constexpr size_t HBUF   = (size_t)3*B*BN*HS;     // 1,916,928 per buffer
constexpr size_t O_HA   = O_KN + XBUF;
constexpr size_t O_HB   = O_HA + HBUF;
constexpr size_t O_Q    = O_HB + HBUF;           // 3,932,992
constexpr size_t QBUF_H = (size_t)B*T*E/2;       // bf16 buffer in float units (2,097,152)
constexpr size_t O_K    = O_Q + QBUF_H;
constexpr size_t O_V    = O_K + QBUF_H;          // V stored TRANSPOSED: [E][B*T] bf16
constexpr size_t O_PO_HI= O_V + QBUF_H;          // splits 0..2 (3 x QBUF_H) -> end 66.06 MB (proven OK)
// packed weights overlay the PO_hi region (dead until attn writes it):
// wA: conv_mid A-fragment prepack, split-bf16: 3*5*30*2*512 ushort = 460,800 ush = 230,400 fl
constexpr size_t O_WPM  = O_PO_HI;
constexpr size_t O_WPO  = O_WPM + (size_t)245760;        // keep old slot size; wA fits (230,400 < 245,760)
// split 3 + m/l overlay the (already-consumed) qn/kn/h region:
constexpr size_t O_PO_LO= O_QN;                  // 1 split
constexpr size_t O_MLM  = O_PO_LO + QBUF_H;      // 4*B*T floats
constexpr size_t O_MLL  = O_MLM + (size_t)4*B*T; // 4*B*T floats (region consumed before attn)

typedef __attribute__((ext_vector_type(8))) short bfrag;
typedef __attribute__((ext_vector_type(4))) float f32x4;
typedef __attribute__((ext_vector_type(16))) float f32x16;
typedef __attribute__((ext_vector_type(4))) unsigned int u32x4;
typedef __attribute__((ext_vector_type(2))) unsigned int u32x2;

DEVI short f2bf(float f){            // fp32 -> bf16 bits, round-to-nearest-even
  uint32_t u = __builtin_bit_cast(uint32_t, f);
  u = u + 0x7fffu + ((u >> 16) & 1u);
  return (short)(u >> 16);
}
DEVI float bf2f(unsigned short u){
  uint32_t x = (uint32_t)u << 16;
  return __builtin_bit_cast(float, x);
}
DEVI uint32_t cvtpk(float a, float b){   // {bf16(b)<<16 | bf16(a)}, HW RNE
  uint32_t d;
  asm("v_cvt_pk_bf16_f32 %0, %1, %2" : "=v"(d) : "v"(a), "v"(b));
  return d;
}
DEVI f32x16 vzero16(){
  f32x16 v;
  #pragma unroll
  for (int i = 0; i < 16; i++) v[i] = 0.f;
  return v;
}

// 16B global -> LDS DMA. LDS dest must be WAVE-UNIFORM base; HW adds lane*16.
DEVI void gload16(const unsigned short* g, short* l){
  __builtin_amdgcn_global_load_lds((const __attribute__((address_space(1))) void*)g,
                                   (__attribute__((address_space(3))) void*)l, 16, 0, 0);
}

// fused prep: [0,1536) h halos, 1536 qn/kn pads, [1537,2437) conv_mid wA prepack
// (split-bf16 A-fragments), [2437,2533) conv_out weight pack, [2533,2557) RevIN.
__global__ __launch_bounds__(256) void k_prep(
    float* __restrict__ ws,
    const float* __restrict__ query_in, const float* __restrict__ key_in,
    const float* __restrict__ revin_w, const float* __restrict__ revin_b,
    const float* __restrict__ qm, const float* __restrict__ km, const float* __restrict__ vm,
    const float* __restrict__ qo, const float* __restrict__ ko, const float* __restrict__ vo){
  __shared__ float r1[256], r2[256];
  __shared__ float sm, sinv;
  const int r = blockIdx.x;
  if (r < 1536){
    float* row = ws + (r < 768 ? O_HA : O_HB) + (size_t)(r & 767)*HS;
    const int t = threadIdx.x;
    if (t < HPAD) row[t] = 0.f;                 // head [0, 224)
    else if (t < 2*HPAD) row[T + t] = 0.f;      // tail [HPAD+T, HS)
  } else if (r == 1536){
    for (int z = threadIdx.x; z < 768; z += 256){
      int buf = z >= 384; int zz = z & 383;
      int rw = zz >> 4; int p = zz & 15;
      float* base = ws + (buf ? O_KN : O_QN) + (size_t)rw*XS;
      base[p < 8 ? p : (XPAD + T + p - 8)] = 0.f;
    }
  } else if (r < 2437){
    // conv_mid A-frag prepack: wA[(netlyr*30+kb)*1024 + half*512 + lane*8 + j] (ushort)
    // kb=(kk<<1)|i16; lane l: o=l&31, hi=l>>5; element j -> W[o][i=i16*16+hi*8+j][kk].
    // half 0 = bf16(w), half 1 = bf16(w - hi_part)  (split-bf16, ~2^-17 rel error)
    unsigned short* wA = (unsigned short*)(ws + O_WPM);
    int p = (r - 1537)*256 + threadIdx.x;       // [0, 230400)
    int j  = p & 7;
    int l  = (p >> 3) & 63;
    int kb = (p >> 9) % 30;
    int netlyr = p / 15360;                      // [0,15)
    int net = netlyr / 5, lyr = netlyr % 5;
    int o  = l & 31, hi = l >> 5;
    int i  = (kb & 1)*16 + hi*8 + j;
    int kk = kb >> 1;
    const float* src = (net==0 ? qm : (net==1 ? km : vm));
    float w = src[(((size_t)lyr*32 + o)*32 + i)*15 + kk];
    unsigned short wh = (unsigned short)f2bf(w);
    unsigned short wl = (unsigned short)f2bf(w - bf2f(wh));
    size_t base = ((size_t)(netlyr*30 + kb))*1024 + l*8 + j;
    wA[base]       = wh;
    wA[base + 512] = wl;
  } else if (r < 2533){
    // conv_out weight pack: [net][i][e]
    float* wpo = ws + O_WPO;
    int idx = (r - 2437)*256 + threadIdx.x;     // [0, 24576)
    int e = idx & 255;
    int i = (idx >> 8) & 31;
    int net = idx >> 13;
    const float* src = (net==0 ? qo : (net==1 ? ko : vo));
    wpo[idx] = src[(size_t)e*32 + i];
  } else {
    // RevIN stats + norm for one (b,c)
    const int bc = r - 2533;
    const int b = bc / C, c = bc % C;
    float* meanp = ws + O_MEAN; float* stdp = ws + O_STD;
    float* qn = ws + O_QN;      float* kn = ws + O_KN;
    float s = 0.f, s2 = 0.f;
    for (int t = threadIdx.x; t < T; t += 256){
      float v = key_in[((size_t)(b*T) + t)*C + c];
      s += v; s2 += v*v;
    }
    r1[threadIdx.x] = s; r2[threadIdx.x] = s2;
    __syncthreads();
    for (int st = 128; st > 0; st >>= 1){
      if (threadIdx.x < st){ r1[threadIdx.x] += r1[threadIdx.x+st]; r2[threadIdx.x] += r2[threadIdx.x+st]; }
      __syncthreads();
    }
    if (threadIdx.x == 0){
      float m = r1[0] / (float)T;
      float var = r2[0] / (float)T - m*m;
      float sd = sqrtf(var + EPS);
      meanp[bc] = m; stdp[bc] = sd; sm = m; sinv = 1.f/sd;
    }
    __syncthreads();
    const float m = sm, inv = sinv, wvv = revin_w[c], bvv = revin_b[c];
    for (int t = threadIdx.x; t < T; t += 256){
      size_t src = ((size_t)(b*T) + t)*C + c;
      size_t dst = ((size_t)(b*C) + c)*XS + XPAD + t;
      qn[dst] = (query_in[src] - m) * inv * wvv + bvv;
      kn[dst] = (key_in[src]   - m) * inv * wvv + bvv;
    }
  }
}

// conv in: C=3 -> BN=32, k=15, dil=1, ReLU. grid = 3*B*BN, block = one (net,b,o) row.
__global__ __launch_bounds__(256) void k_conv_in(
    const float* __restrict__ qn, const float* __restrict__ kn,
    const float* __restrict__ wq, const float* __restrict__ bq,
    const float* __restrict__ wk, const float* __restrict__ bk,
    const float* __restrict__ wv, const float* __restrict__ bv,
    float* __restrict__ hout){
  __shared__ float xs[C*XS];
  const int net = blockIdx.x / (B*BN);
  const int rem = blockIdx.x % (B*BN);
  const int b = rem / BN, o = rem % BN;
  const float* x    = (net==0 ? qn : kn) + (size_t)b*C*XS;
  const float* w    = (net==0 ? wq : (net==1 ? wk : wv)) + o*C*KW;
  const float* bias = (net==0 ? bq : (net==1 ? bk : bv));
  for (int i = threadIdx.x; i < C*XS; i += 256) xs[i] = x[i];
  __syncthreads();
  const float bo = bias[o];
  float* orow = hout + (((size_t)(net*B + b))*BN + o)*HS + HPAD;
  for (int j = 0; j < 8; j++){
    int t = j*256 + threadIdx.x;
    float acc = bo;
    #pragma unroll
    for (int c = 0; c < C; c++)
      #pragma unroll
      for (int kk = 0; kk < KW; kk++)
        acc += xs[c*XS + XPAD + t + kk - 7] * w[c*KW + kk];
    orow[t] = fmaxf(acc, 0.f);
  }
}

// dilated conv BN->BN as split-bf16 MFMA GEMM. grid = 3*8*16 = 384, 256 thr (4 waves).
// M=32 (o), N=128 (t-tile; wave wv owns t in [wv*32, wv*32+32)), K=480 = 30 steps of 16.
//   A = W prepacked (hi+lo), B = X^T staged in LDS bf16 (80B rows, conflict-free),
//   D[col=l&31 = t][row r -> o=(r&3)+8*(r>>2)+4*hi]. 3 chains: Ah*Bh + Ah*Bl + Al*Bh.
template<int DIL>
__global__ __launch_bounds__(256) void k_conv_mid(
    const float* __restrict__ hin, float* __restrict__ hout,
    const unsigned short* __restrict__ wA,
    const float* __restrict__ bq, const float* __restrict__ bk, const float* __restrict__ bv,
    int layer){
  constexpr int WT  = 128 + 14*DIL;              // staged t-window rows
  constexpr int NRR = (WT + 15)/16;
  __shared__ __align__(16) unsigned short Xh[WT*40];
  __shared__ __align__(16) unsigned short Xl[WT*40];

  const int net = blockIdx.x >> 7;               // 128 blocks per net
  const int rem = blockIdx.x & 127;
  const int b  = rem >> 4;
  const int tt = rem & 15;
  const int netb = net*B + b;
  const int tid  = threadIdx.x;
  const int wv   = __builtin_amdgcn_readfirstlane(tid >> 6);
  const int lane = tid & 63;
  const int l5   = lane & 31;
  const int hi   = lane >> 5;

  // ---- stage X^T (bf16 split) ----
  {
    const int ip = tid >> 4;                     // i-pair 0..15 (i = 2*ip, 2*ip+1)
    const int tl = tid & 15;                     // lanes 0-15 consecutive t -> coalesced
    const int gt0 = HPAD + tt*128 - 7*DIL;       // >= 0 (HPAD = 224 = 7*32)
    const float* r0 = hin + ((size_t)(netb*32 + 2*ip))*HS + gt0;
    const float* r1 = r0 + HS;
    unsigned int* xhw = (unsigned int*)Xh;
    unsigned int* xlw = (unsigned int*)Xl;
    #pragma unroll
    for (int rr = 0; rr < NRR; rr++){
      int t = rr*16 + tl;
      if (t < WT){
        float a = r0[t], bb = r1[t];
        uint32_t hp = cvtpk(a, bb);
        float la = a  - bf2f((unsigned short)(hp & 0xffffu));
        float lb = bb - bf2f((unsigned short)(hp >> 16));
        uint32_t lp = cvtpk(la, lb);
        xhw[t*20 + ip] = hp;
        xlw[t*20 + ip] = lp;
      }
    }
  }
  __syncthreads();

  // ---- MFMA K-loop ----
  const unsigned short* wAl = wA + (size_t)(net*5 + layer)*30*1024;
  f32x16 a0 = vzero16(), a1 = vzero16(), a2 = vzero16();
  #pragma unroll 6
  for (int kb = 0; kb < 30; kb++){
    const int kk  = kb >> 1;
    const int i16 = kb & 1;
    bfrag Ah = *(const bfrag*)(wAl + (size_t)kb*1024 + lane*8);
    bfrag Al = *(const bfrag*)(wAl + (size_t)kb*1024 + 512 + lane*8);
    const int row = wv*32 + l5 + kk*DIL;         // <= 127 + 14*DIL = WT-1
    bfrag Bh = *(const bfrag*)&Xh[row*40 + (i16*2 + hi)*8];
    bfrag Bl = *(const bfrag*)&Xl[row*40 + (i16*2 + hi)*8];
    a0 = __builtin_amdgcn_mfma_f32_32x32x16_bf16(Ah, Bh, a0, 0, 0, 0);
    a1 = __builtin_amdgcn_mfma_f32_32x32x16_bf16(Ah, Bl, a1, 0, 0, 0);
    a2 = __builtin_amdgcn_mfma_f32_32x32x16_bf16(Al, Bh, a2, 0, 0, 0);
  }

  // ---- epilogue: bias + ReLU, store [o][t] (per r: 2x128B coalesced) ----
  const float* bias = (net==0 ? bq : (net==1 ? bk : bv)) + layer*BN;
  const int tg = tt*128 + wv*32 + l5;
  float* obase = hout + ((size_t)netb*32)*HS + HPAD + tg;
  #pragma unroll
  for (int g = 0; g < 4; g++){
    float4 bg = *(const float4*)(bias + g*8 + 4*hi);
    #pragma unroll
    for (int q = 0; q < 4; q++){
      int o = g*8 + 4*hi + q;
      float v = a0[g*4+q] + a1[g*4+q] + a2[g*4+q] + ((const float*)&bg)[q];
      obase[(size_t)o*HS] = fmaxf(v, 0.f);
    }
  }
}

// 1x1 conv BN -> E, bf16 out, packed weights; q pre-scaled by E^-0.5. grid = 1536.
// V (net==2) is written TRANSPOSED [E][B*T] so attention can stage it coalesced.
__global__ __launch_bounds__(256) void k_conv_out(
    const float* __restrict__ hin, const float* __restrict__ wpo,
    const float* __restrict__ bq, const float* __restrict__ bk, const float* __restrict__ bv,
    unsigned short* __restrict__ qo, unsigned short* __restrict__ ko, unsigned short* __restrict__ vo){
  const int net = blockIdx.x >> 9;
  const int rem = blockIdx.x & 511;
  const int b = rem >> 6;
  const int tt = (rem & 63) >> 2;
  const int eq = rem & 3;
  const int wave = __builtin_amdgcn_readfirstlane(threadIdx.x >> 6);
  const int lane = threadIdx.x & 63;
  const int t0 = tt*128 + lane*2;
  const int e_base = eq*64 + wave*16;
  const float* wb   = wpo + (size_t)net*32*256 + e_base;   // + i*256 per i
  const float* bias = (net==0 ? bq : (net==1 ? bk : bv)) + e_base;
  float acc[16][2];
  #pragma unroll
  for (int j = 0; j < 16; j++){ acc[j][0] = 0.f; acc[j][1] = 0.f; }
  const float* hb = hin + (((size_t)(net*B + b))*BN)*HS + HPAD + t0;
  for (int i = 0; i < BN; i++){
    const float2 xv = *(const float2*)(hb + (size_t)i*HS);
    const float* wi = wb + i*256;
    #pragma unroll
    for (int j = 0; j < 16; j++){
      const float wj = wi[j];
      acc[j][0] += wj*xv.x; acc[j][1] += wj*xv.y;
    }
  }
  if (net != 2){
    const float scale = (net==0) ? 0.0625f : 1.0f;
    unsigned short* outp = (net==0 ? qo : ko);
    #pragma unroll
    for (int z = 0; z < 2; z++){
      bfrag pk[2];
      #pragma unroll
      for (int j = 0; j < 16; j++)
        pk[j>>3][j&7] = f2bf((acc[j][z] + bias[j]) * scale);
      size_t dst = ((size_t)(b*T) + t0 + z)*E + e_base;
      *(bfrag*)&outp[dst]     = pk[0];
      *(bfrag*)&outp[dst + 8] = pk[1];
    }
  } else {
    // transposed V: vo[e][b*T + t]; pack the two adjacent-t bf16 into one dword store.
    unsigned int* vt = (unsigned int*)vo;
    #pragma unroll
    for (int j = 0; j < 16; j++){
      unsigned int lo = (unsigned short)f2bf(acc[j][0] + bias[j]);
      unsigned int hi = (unsigned short)f2bf(acc[j][1] + bias[j]);
      size_t idx = (size_t)(e_base + j)*((size_t)B*T) + (size_t)b*T + t0;
      vt[idx >> 1] = lo | (hi << 16);
    }
  }
}

// flash attention v2: 32x32 MFMA, swapped operands, in-register softmax.
// BQ=128 (4 waves x 32 q-rows, 256 thr), BK=32, split-K=4. grid = B*16*4 = 512.
// Register budget is EXACTLY full at (256,2): acc 128 + b_q 64 + temps = 256 combined.
// r11 proved adding any transient chain state spills (-25%); do not touch.
__global__ __launch_bounds__(256, 2) void k_attn(
    const unsigned short* __restrict__ qbuf, const unsigned short* __restrict__ kbuf,
    const unsigned short* __restrict__ vbufT,
    unsigned short* __restrict__ PO_hi, unsigned short* __restrict__ PO_lo,
    float* __restrict__ MLm, float* __restrict__ MLl){
  __shared__ __align__(16) short Ks[2][32*256];   // K tile, key-major, 512B/row, granule^key&7
  __shared__ __align__(16) short Vs[2][256*32];   // V^T tile, e-major, 64B/row, granule^(e>>1)&3

  const int nid  = ((blockIdx.x & 7) << 6) | (blockIdx.x >> 3);
  const int s    = nid & 3;
  const int qt   = (nid >> 2) & 15;
  const int b    = nid >> 6;
  const int tid  = threadIdx.x;
  const int wv   = __builtin_amdgcn_readfirstlane(tid >> 6);
  const int lane = tid & 63;
  const int l5   = lane & 31;
  const int hi   = lane >> 5;
  const int qrow_base = qt*128 + wv*32;

  bfrag b_q[16];
  {
    const unsigned short* qp = qbuf + ((size_t)(b*T) + qrow_base + l5)*E + hi*8;
    #pragma unroll
    for (int st = 0; st < 16; st++)
      b_q[st] = *(const bfrag*)&qp[st*16];
  }

  f32x16 acc[8];
  #pragma unroll
  for (int nt = 0; nt < 8; nt++) acc[nt] = vzero16();
  float m_run = -1e30f, l_run = 0.f;

  const unsigned short* gks[4]; const unsigned short* gvs[4];
  #pragma unroll
  for (int u = 0; u < 4; u++){
    int lin = u*256 + tid;
    int kr = lin >> 5, kg = lin & 31;
    gks[u] = kbuf + ((size_t)(b*T) + kr)*E + ((kg ^ (kr & 7)) << 3);
    int ve = lin >> 2, vg = lin & 3;
    gvs[u] = vbufT + (size_t)ve*((size_t)B*T) + (size_t)b*T + ((vg ^ ((ve >> 1) & 3)) << 3);
  }
  auto stage = [&](int buf, int j0){
    #pragma unroll
    for (int u = 0; u < 4; u++)
      gload16(gks[u] + (size_t)j0*E, &Ks[buf][u*2048 + wv*512]);
    #pragma unroll
    for (int u = 0; u < 4; u++)
      gload16(gvs[u] + j0, &Vs[buf][u*2048 + wv*512]);
  };

  const int x7 = l5 & 7;
  const int vx = (l5 >> 1) & 3;

  const int kend = s*16 + 16;
  stage(0, s*16*32);
  __syncthreads();
  int cur = 0;

  for (int kbk = s*16; kbk < kend; kbk++){
    if (kbk + 1 < kend) stage(cur ^ 1, (kbk+1)*32);

    f32x16 sac = vzero16();
    __builtin_amdgcn_s_setprio(1);
    #pragma unroll
    for (int st = 0; st < 16; st++){
      bfrag ka = *(const bfrag*)&Ks[cur][l5*256 + ((((st << 1) | hi) ^ x7) << 3)];
      sac = __builtin_amdgcn_mfma_f32_32x32x16_bf16(ka, b_q[st], sac, 0, 0, 0);
    }
    __builtin_amdgcn_s_setprio(0);

    float mloc = sac[0];
    #pragma unroll
    for (int r = 1; r < 16; r++) mloc = fmaxf(mloc, sac[r]);
    mloc = fmaxf(mloc, __shfl_xor(mloc, 32));

    if (__ballot(mloc > m_run + 8.f)){
      float mn = fmaxf(m_run, mloc);
      float alpha = __expf(m_run - mn);
      m_run = mn;
      l_run *= alpha;
      #pragma unroll
      for (int nt = 0; nt < 8; nt++)
        #pragma unroll
        for (int r = 0; r < 16; r++) acc[nt][r] *= alpha;
    }
    float p[16]; float ls = 0.f;
    #pragma unroll
    for (int r = 0; r < 16; r++){
      p[r] = __expf(sac[r] - m_run);
      ls += p[r];
    }
    l_run += ls;

    uint32_t pk[8], xk[8];
    #pragma unroll
    for (int r = 0; r < 8; r++)
      pk[r] = cvtpk(p[2*r], p[2*r+1]);
    #pragma unroll
    for (int r = 0; r < 8; r++) xk[r] = __shfl_xor(pk[r], 32);
    u32x4 w0, w1;
    w0[0] = hi ? xk[2] : pk[0];  w0[1] = hi ? xk[3] : pk[1];
    w0[2] = hi ? pk[2] : xk[0];  w0[3] = hi ? pk[3] : xk[1];
    w1[0] = hi ? xk[6] : pk[4];  w1[1] = hi ? xk[7] : pk[5];
    w1[2] = hi ? pk[6] : xk[4];  w1[3] = hi ? pk[7] : xk[5];
    bfrag pf0 = __builtin_bit_cast(bfrag, w0);
    bfrag pf1 = __builtin_bit_cast(bfrag, w1);

    __builtin_amdgcn_s_setprio(1);
    #pragma unroll
    for (int nt = 0; nt < 8; nt++){
      bfrag v0 = *(const bfrag*)&Vs[cur][(nt*32 + l5)*32 + (((0 | hi) ^ vx) << 3)];
      acc[nt] = __builtin_amdgcn_mfma_f32_32x32x16_bf16(v0, pf0, acc[nt], 0, 0, 0);
      bfrag v1 = *(const bfrag*)&Vs[cur][(nt*32 + l5)*32 + (((2 | hi) ^ vx) << 3)];
      acc[nt] = __builtin_amdgcn_mfma_f32_32x32x16_bf16(v1, pf1, acc[nt], 0, 0, 0);
    }
    __builtin_amdgcn_s_setprio(0);

    __syncthreads();
    cur ^= 1;
  }

  l_run += __shfl_xor(l_run, 32);
  const float inv_l = 1.f / l_run;
  const int row = qrow_base + l5;
  unsigned short* PO = (s < 3) ? (PO_hi + (size_t)s*((size_t)B*T*E)) : PO_lo;
  const size_t off = ((size_t)(b*T) + row)*E;
  #pragma unroll
  for (int nt = 0; nt < 8; nt++){
    #pragma unroll
    for (int g = 0; g < 4; g++){
      const int e0 = nt*32 + 8*g + 4*hi;
      u32x2 wpair;
      wpair[0] = cvtpk(acc[nt][g*4+0]*inv_l, acc[nt][g*4+1]*inv_l);
      wpair[1] = cvtpk(acc[nt][g*4+2]*inv_l, acc[nt][g*4+3]*inv_l);
      *(u32x2*)&PO[off + e0] = wpair;
    }
  }
  if (hi == 0){
    const size_t rm = ((size_t)(s*B + b))*T + row;
    MLm[rm] = m_run;
    MLl[rm] = l_run;
  }
}

// combine 4 splits + out-projection + RevIN denorm. grid = B*T/32 = 512, 256 thr.
__global__ __launch_bounds__(256) void k_comb(
    const unsigned short* __restrict__ PO_hi, const unsigned short* __restrict__ PO_lo,
    const float* __restrict__ MLm, const float* __restrict__ MLl,
    const float* __restrict__ out_w, const float* __restrict__ out_b,
    const float* __restrict__ revin_w, const float* __restrict__ revin_b,
    const float* __restrict__ meanp, const float* __restrict__ stdp,
    float* __restrict__ out){
  __shared__ float wsh[3*E];
  for (int i = threadIdx.x; i < 3*E; i += 256) wsh[i] = out_w[i];
  __syncthreads();
  const int b  = blockIdx.x >> 6;
  const int rt = blockIdx.x & 63;
  const int row = rt*32 + (threadIdx.x >> 3);
  const int c8 = threadIdx.x & 7;
  const int e0 = c8*32;
  float ms[4], ls[4], wn[4];
  #pragma unroll
  for (int s2 = 0; s2 < 4; s2++){
    const size_t rm = ((size_t)(s2*B + b))*T + row;
    ms[s2] = MLm[rm]; ls[s2] = MLl[rm];
  }
  float mx = fmaxf(fmaxf(ms[0], ms[1]), fmaxf(ms[2], ms[3]));
  float wsum = 0.f;
  #pragma unroll
  for (int s2 = 0; s2 < 4; s2++){ wn[s2] = __expf(ms[s2]-mx)*ls[s2]; wsum += wn[s2]; }
  float inv = 1.f/wsum;
  #pragma unroll
  for (int s2 = 0; s2 < 4; s2++) wn[s2] *= inv;
  const unsigned short* ps[4];
  #pragma unroll
  for (int s2 = 0; s2 < 4; s2++){
    const unsigned short* base = (s2 < 3) ? (PO_hi + (size_t)s2*((size_t)B*T*E)) : PO_lo;
    ps[s2] = base + ((size_t)(b*T) + row)*E + e0;
  }
  float pr[3] = {0.f, 0.f, 0.f};
  #pragma unroll
  for (int u = 0; u < 4; u++){
    float v[8] = {0,0,0,0,0,0,0,0};
    #pragma unroll
    for (int s2 = 0; s2 < 4; s2++){
      bfrag a = *(const bfrag*)&ps[s2][u*8];
      #pragma unroll
      for (int z = 0; z < 8; z++) v[z] += wn[s2]*bf2f((unsigned short)a[z]);
    }
    #pragma unroll
    for (int z = 0; z < 8; z++){
      int e = e0 + u*8 + z;
      pr[0] += v[z]*wsh[e];
      pr[1] += v[z]*wsh[E + e];
      pr[2] += v[z]*wsh[2*E + e];
    }
  }
  #pragma unroll
  for (int c = 0; c < 3; c++){
    pr[c] += __shfl_xor(pr[c], 1);
    pr[c] += __shfl_xor(pr[c], 2);
    pr[c] += __shfl_xor(pr[c], 4);
  }
  if (c8 == 0){
    #pragma unroll
    for (int c = 0; c < 3; c++){
      float val = pr[c] + out_b[c];
      val = (val - revin_b[c]) / revin_w[c];
      val = val * stdp[b*C + c] + meanp[b*C + c];
      out[((size_t)(b*T) + row)*C + c] = val;
    }
  }
}

} // namespace

extern "C" void kernel_launch(void* const* d_in, const int* in_sizes, int n_in,
                              void* d_out, int out_size, void* d_ws, size_t ws_size,
                              hipStream_t stream){
  const float* query_in = (const float*)d_in[0];
  const float* key_in   = (const float*)d_in[1];
  const float* q_w_in   = (const float*)d_in[2];
  const float* q_b_in   = (const float*)d_in[3];
  const float* q_w_mid  = (const float*)d_in[4];
  const float* q_b_mid  = (const float*)d_in[5];
  const float* q_w_out  = (const float*)d_in[6];
  const float* q_b_out  = (const float*)d_in[7];
  const float* k_w_in   = (const float*)d_in[8];
  const float* k_b_in   = (const float*)d_in[9];
  const float* k_w_mid  = (const float*)d_in[10];
  const float* k_b_mid  = (const float*)d_in[11];
  const float* k_w_out  = (const float*)d_in[12];
  const float* k_b_out  = (const float*)d_in[13];
  const float* v_w_in   = (const float*)d_in[14];
  const float* v_b_in   = (const float*)d_in[15];
  const float* v_w_mid  = (const float*)d_in[16];
  const float* v_b_mid  = (const float*)d_in[17];
  const float* v_w_out  = (const float*)d_in[18];
  const float* v_b_out  = (const float*)d_in[19];
  const float* out_w    = (const float*)d_in[20];
  const float* out_b    = (const float*)d_in[21];
  const float* revin_w  = (const float*)d_in[22];
  const float* revin_b  = (const float*)d_in[23];
  float* ws  = (float*)d_ws;
  float* out = (float*)d_out;

  unsigned short* qb = (unsigned short*)(ws + O_Q);
  unsigned short* kb = (unsigned short*)(ws + O_K);
  unsigned short* vb = (unsigned short*)(ws + O_V);
  unsigned short* PO_hi = (unsigned short*)(ws + O_PO_HI);
  unsigned short* PO_lo = (unsigned short*)(ws + O_PO_LO);
  float* MLm = ws + O_MLM;
  float* MLl = ws + O_MLL;
  unsigned short* wA = (unsigned short*)(ws + O_WPM);
  float* wpo = ws + O_WPO;

  hipLaunchKernelGGL(k_prep, dim3(2557), dim3(256), 0, stream,
                     ws, query_in, key_in, revin_w, revin_b,
                     q_w_mid, k_w_mid, v_w_mid, q_w_out, k_w_out, v_w_out);
  hipLaunchKernelGGL(k_conv_in, dim3(3*B*BN), dim3(256), 0, stream,
                     ws+O_QN, ws+O_KN, q_w_in, q_b_in, k_w_in, k_b_in, v_w_in, v_b_in, ws+O_HA);
  float* ha = ws + O_HA;
  float* hb = ws + O_HB;
  hipLaunchKernelGGL(k_conv_mid<2>,  dim3(384), dim3(256), 0, stream, ha, hb,
                     wA, q_b_mid, k_b_mid, v_b_mid, 0);
  hipLaunchKernelGGL(k_conv_mid<4>,  dim3(384), dim3(256), 0, stream, hb, ha,
                     wA, q_b_mid, k_b_mid, v_b_mid, 1);
  hipLaunchKernelGGL(k_conv_mid<8>,  dim3(384), dim3(256), 0, stream, ha, hb,
                     wA, q_b_mid, k_b_mid, v_b_mid, 2);
  hipLaunchKernelGGL(k_conv_mid<16>, dim3(384), dim3(256), 0, stream, hb, ha,
                     wA, q_b_mid, k_b_mid, v_b_mid, 3);
  hipLaunchKernelGGL(k_conv_mid<32>, dim3(384), dim3(256), 0, stream, ha, hb,
                     wA, q_b_mid, k_b_mid, v_b_mid, 4);
  hipLaunchKernelGGL(k_conv_out, dim3(1536), dim3(256), 0, stream,
                     hb, wpo, q_b_out, k_b_out, v_b_out, qb, kb, vb);
  hipLaunchKernelGGL(k_attn, dim3(B*16*4), dim3(256), 0, stream, qb, kb, vb, PO_hi, PO_lo, MLm, MLl);
  hipLaunchKernelGGL(k_comb, dim3(B*T/32), dim3(256), 0, stream,
                     PO_hi, PO_lo, MLm, MLl, out_w, out_b, revin_w, revin_b, ws+O_MEAN, ws+O_STD, out);
}